// Round 4
// baseline (389.092 us; speedup 1.0000x reference)
//
#include <hip/hip_runtime.h>

// Causal flash attention, B=4 H=16 S=2048 D=64, fp32 in/out, bf16 MFMA.
// R4: wave-per-q-strip, barrier-free k-loop. Preconv writes K/V bf16 tile
// images in FRAGMENT-LINEAR order; each wave loads its MFMA frags directly
// global->VGPR (perfectly coalesced, L2/L3-resident stream), so LDS carries
// only the P (C-layout -> A-layout) round-trip and the k-loop has no
// __syncthreads at all. Blocks = 2 waves pairing strips (16+s, 15-s):
// every block exactly 33 tile-units -> uniform load across all 1024 blocks.

#define S_LEN 2048
#define D_HEAD 64
#define NBH 64      // B*H
#define QBLK 32     // S / 64 (64-row strips)
#define TILE_E 4096 // 64x64 elements per tile image

typedef float f32x4 __attribute__((ext_vector_type(4)));
typedef short s16x8 __attribute__((ext_vector_type(8)));

#define SCLOG2E (0.125f * 1.44269504088896340736f)  // 1/sqrt(D) * log2(e)

__device__ __forceinline__ unsigned short f2bf(float x) {  // RNE
    union { float f; unsigned int u; } v; v.f = x;
    unsigned int u = v.u + 0x7FFFu + ((v.u >> 16) & 1u);
    return (unsigned short)(u >> 16);
}
__device__ __forceinline__ unsigned short f2bf_hu(float x) { // half-up (P path)
    union { float f; unsigned int u; } v; v.f = x;
    return (unsigned short)((v.u + 0x8000u) >> 16);
}

// chunk-rotation swizzle for 64-wide bf16 rows (verified: 0 bank conflicts)
__device__ __forceinline__ int swz(int row, int col) {
    return row * 64 + ((((col >> 3) + row) & 7) << 3) + (col & 7);
}

// ---------- pre-pass: fp32 K,V -> bf16 FRAGMENT-LINEAR tile images ----------
// Image layout per 64x64 tile (4096 elems): idx = inst*512 + lane*8 + e,
// inst = kt2*4+nt.  Kw: K[key=nt*16+(lane&15)][d=(4*kt2+(lane>>4))*8+e]
//                   Vw: V[key=(4*kt2+(lane>>4))*8+e][d=nt*16+(lane&15)]
__global__ __launch_bounds__(256)
void preconv_kernel(const float* __restrict__ K, const float* __restrict__ V,
                    unsigned short* __restrict__ Kw, unsigned short* __restrict__ Vw)
{
    __shared__ __align__(16) unsigned short kt[TILE_E];  // [key][d] swizzled
    __shared__ __align__(16) unsigned short vt[TILE_E];  // [d][key] swizzled
    const int bh = blockIdx.x & (NBH - 1);
    const int j  = blockIdx.x >> 6;
    const float* k = K + (size_t)bh * (S_LEN * D_HEAD) + (size_t)j * 64 * D_HEAD;
    const float* v = V + (size_t)bh * (S_LEN * D_HEAD) + (size_t)j * 64 * D_HEAD;
    const int t = threadIdx.x;

#pragma unroll
    for (int i = 0; i < 2; ++i) {   // K tile, row-major [key][d], swizzled
        int chunk = t + 256 * i;
        int row = chunk >> 3, c = chunk & 7;
        const float* p = k + (size_t)row * D_HEAD + c * 8;
        float4 x = *(const float4*)p;
        float4 y = *(const float4*)(p + 4);
        s16x8 f;
        f[0] = (short)f2bf(x.x); f[1] = (short)f2bf(x.y);
        f[2] = (short)f2bf(x.z); f[3] = (short)f2bf(x.w);
        f[4] = (short)f2bf(y.x); f[5] = (short)f2bf(y.y);
        f[6] = (short)f2bf(y.z); f[7] = (short)f2bf(y.w);
        *(s16x8*)&kt[swz(row, c * 8)] = f;
    }
    {   // V tile, transposed [d][key], swizzled
        int key = t & 63, cc = t >> 6;
#pragma unroll
        for (int ci = 0; ci < 2; ++ci) {
            int c = cc + ci * 4;
            const float* p = v + (size_t)key * D_HEAD + c * 8;
            float4 x = *(const float4*)p;
            float4 y = *(const float4*)(p + 4);
            float vals[8] = {x.x, x.y, x.z, x.w, y.x, y.y, y.z, y.w};
#pragma unroll
            for (int jj = 0; jj < 8; ++jj)
                vt[swz(c * 8 + jj, key)] = f2bf(vals[jj]);
        }
    }
    __syncthreads();
    // dump in fragment-linear order (frag reads = the known conflict-free
    // pattern; global writes 1KB-contiguous per wave-instruction)
    const size_t tb = (size_t)(bh * QBLK + j) * TILE_E;
    const int w = t >> 6, lane = t & 63, col = lane & 15, quad = lane >> 4;
#pragma unroll
    for (int i = 0; i < 2; ++i) {
        int inst = w * 2 + i;
        int kt2 = inst >> 2, nt = inst & 3;
        s16x8 kf = *(const s16x8*)&kt[swz(nt * 16 + col, (4 * kt2 + quad) * 8)];
        s16x8 vf = *(const s16x8*)&vt[swz(nt * 16 + col, (4 * kt2 + quad) * 8)];
        *(s16x8*)&Kw[tb + inst * 512 + lane * 8] = kf;
        *(s16x8*)&Vw[tb + inst * 512 + lane * 8] = vf;
    }
}

// ---------------------------- main kernel -----------------------------------
template <bool PRE>
__global__ __launch_bounds__(128, 2)
void fattn_kernel(const float* __restrict__ Qg, const float* __restrict__ Kg,
                  const float* __restrict__ Vg, float* __restrict__ Og,
                  const unsigned short* __restrict__ Kw,
                  const unsigned short* __restrict__ Vw)
{
    __shared__ __align__(16) unsigned short ps[2][TILE_E];  // per-wave 64x64 P

    const int bx = blockIdx.x;
    const int bh = bx & (NBH - 1);
    const int s  = bx >> 6;          // [0,16)
    const int t    = threadIdx.x;
    const int w    = t >> 6;
    const int lane = t & 63;
    const int col  = lane & 15;
    const int quad = lane >> 4;
    const int qs   = w ? (15 - s) : (16 + s);   // strip pair: equal block work

    const size_t base = (size_t)bh * (S_LEN * D_HEAD);
    const float* q = Qg + base;
    const float* k = Kg + base;
    const float* v = Vg + base;
    float*       o = Og + base;

    // Q fragments (A-layout): 4 m-tiles x 2 k-halves
    s16x8 qa[4][2];
#pragma unroll
    for (int m = 0; m < 4; ++m) {
        const int qr = qs * 64 + m * 16 + col;
        const float* p0 = q + (size_t)qr * D_HEAD + quad * 8;
#pragma unroll
        for (int kt2 = 0; kt2 < 2; ++kt2) {
            const float* p = p0 + kt2 * 32;
            float4 x = *(const float4*)(p);
            float4 y = *(const float4*)(p + 4);
            s16x8 f;
            f[0] = (short)f2bf(x.x); f[1] = (short)f2bf(x.y);
            f[2] = (short)f2bf(x.z); f[3] = (short)f2bf(x.w);
            f[4] = (short)f2bf(y.x); f[5] = (short)f2bf(y.y);
            f[6] = (short)f2bf(y.z); f[7] = (short)f2bf(y.w);
            qa[m][kt2] = f;
        }
    }

    s16x8 ones;
#pragma unroll
    for (int i = 0; i < 8; ++i) ones[i] = (short)0x3F80;  // bf16 1.0

    f32x4 oacc[4][4], lf[4];
#pragma unroll
    for (int m = 0; m < 4; ++m) {
        lf[m] = (f32x4){0.f, 0.f, 0.f, 0.f};
#pragma unroll
        for (int nt = 0; nt < 4; ++nt) oacc[m][nt] = (f32x4){0.f, 0.f, 0.f, 0.f};
    }

    s16x8 kb2[2][4], vb[2][4];

    auto loadK = [&](int jt) {
        if constexpr (PRE) {
            const unsigned short* tbp = Kw + (size_t)(bh * QBLK + jt) * TILE_E + lane * 8;
#pragma unroll
            for (int kt2 = 0; kt2 < 2; ++kt2)
#pragma unroll
                for (int nt = 0; nt < 4; ++nt)
                    kb2[kt2][nt] = *(const s16x8*)(tbp + (kt2 * 4 + nt) * 512);
        } else {
#pragma unroll
            for (int kt2 = 0; kt2 < 2; ++kt2)
#pragma unroll
                for (int nt = 0; nt < 4; ++nt) {
                    const float* p = k + (size_t)(jt * 64 + nt * 16 + col) * D_HEAD + (4 * kt2 + quad) * 8;
                    float4 x = *(const float4*)p;
                    float4 y = *(const float4*)(p + 4);
                    s16x8 f;
                    f[0] = (short)f2bf(x.x); f[1] = (short)f2bf(x.y);
                    f[2] = (short)f2bf(x.z); f[3] = (short)f2bf(x.w);
                    f[4] = (short)f2bf(y.x); f[5] = (short)f2bf(y.y);
                    f[6] = (short)f2bf(y.z); f[7] = (short)f2bf(y.w);
                    kb2[kt2][nt] = f;
                }
        }
    };
    auto loadV = [&](int jt) {
        if constexpr (PRE) {
            const unsigned short* tbp = Vw + (size_t)(bh * QBLK + jt) * TILE_E + lane * 8;
#pragma unroll
            for (int kt2 = 0; kt2 < 2; ++kt2)
#pragma unroll
                for (int nt = 0; nt < 4; ++nt)
                    vb[kt2][nt] = *(const s16x8*)(tbp + (kt2 * 4 + nt) * 512);
        } else {
#pragma unroll
            for (int kt2 = 0; kt2 < 2; ++kt2)
#pragma unroll
                for (int nt = 0; nt < 4; ++nt) {
                    s16x8 f;
#pragma unroll
                    for (int e = 0; e < 8; ++e)
                        f[e] = (short)f2bf(v[(size_t)(jt * 64 + (4 * kt2 + quad) * 8 + e) * D_HEAD + nt * 16 + col]);
                    vb[kt2][nt] = f;
                }
        }
    };

    loadK(0);
    loadV(0);

    for (int j = 0; j <= qs; ++j) {
        // ---- S = Q K^T (uses kb2 = tile j)
        f32x4 sf[4][4];
#pragma unroll
        for (int m = 0; m < 4; ++m)
#pragma unroll
            for (int nt = 0; nt < 4; ++nt) sf[m][nt] = (f32x4){0.f, 0.f, 0.f, 0.f};
#pragma unroll
        for (int kt2 = 0; kt2 < 2; ++kt2)
#pragma unroll
            for (int nt = 0; nt < 4; ++nt)
#pragma unroll
                for (int m = 0; m < 4; ++m)
                    sf[m][nt] = __builtin_amdgcn_mfma_f32_16x16x32_bf16(qa[m][kt2], kb2[kt2][nt], sf[m][nt], 0, 0, 0);

        // ---- prefetch K for tile j+1 (kb2 regs now free)
        const int jn = (j < qs) ? (j + 1) : qs;
        loadK(jn);

        // ---- scale (+ diagonal causal mask), exp2, P -> private LDS region
        if (j == qs) {
#pragma unroll
            for (int m = 0; m < 4; ++m)
#pragma unroll
                for (int nt = 0; nt < 4; ++nt) {
                    const int keyl = nt * 16 + col;
                    const int qrl  = m * 16 + quad * 4;
#pragma unroll
                    for (int r = 0; r < 4; ++r)
                        sf[m][nt][r] = (keyl > qrl + r) ? -__builtin_inff() : sf[m][nt][r] * SCLOG2E;
                }
        } else {
#pragma unroll
            for (int m = 0; m < 4; ++m)
#pragma unroll
                for (int nt = 0; nt < 4; ++nt)
#pragma unroll
                    for (int r = 0; r < 4; ++r) sf[m][nt][r] *= SCLOG2E;
        }
#pragma unroll
        for (int m = 0; m < 4; ++m)
#pragma unroll
            for (int nt = 0; nt < 4; ++nt)
#pragma unroll
                for (int r = 0; r < 4; ++r)
                    ps[w][swz(m * 16 + quad * 4 + r, nt * 16 + col)] = f2bf_hu(exp2f(sf[m][nt][r]));

        // ---- P A-frags (in-wave LDS ordering; no barrier needed)
        s16x8 af[4][2];
#pragma unroll
        for (int m = 0; m < 4; ++m)
#pragma unroll
            for (int kt2 = 0; kt2 < 2; ++kt2)
                af[m][kt2] = *(const s16x8*)&ps[w][swz(m * 16 + col, (4 * kt2 + quad) * 8)];

        // ---- l += P*ones, then O += P V (uses vb = tile j)
#pragma unroll
        for (int m = 0; m < 4; ++m)
#pragma unroll
            for (int kt2 = 0; kt2 < 2; ++kt2)
                lf[m] = __builtin_amdgcn_mfma_f32_16x16x32_bf16(af[m][kt2], ones, lf[m], 0, 0, 0);
#pragma unroll
        for (int kt2 = 0; kt2 < 2; ++kt2)
#pragma unroll
            for (int nt = 0; nt < 4; ++nt)
#pragma unroll
                for (int m = 0; m < 4; ++m)
                    oacc[m][nt] = __builtin_amdgcn_mfma_f32_16x16x32_bf16(af[m][kt2], vb[kt2][nt], oacc[m][nt], 0, 0, 0);

        // ---- prefetch V for tile j+1
        loadV(jn);
    }

    // ---- epilogue
#pragma unroll
    for (int m = 0; m < 4; ++m)
#pragma unroll
        for (int r = 0; r < 4; ++r) {
            float inv = 1.f / lf[m][r];
            int row = qs * 64 + m * 16 + quad * 4 + r;
            float* po = o + (size_t)row * D_HEAD;
#pragma unroll
            for (int nt = 0; nt < 4; ++nt) po[nt * 16 + col] = oacc[m][nt][r] * inv;
        }
}

extern "C" void kernel_launch(void* const* d_in, const int* in_sizes, int n_in,
                              void* d_out, int out_size, void* d_ws, size_t ws_size,
                              hipStream_t stream) {
    const float* q = (const float*)d_in[0];
    const float* k = (const float*)d_in[1];
    const float* v = (const float*)d_in[2];
    float* out = (float*)d_out;

    const size_t kv_elems = (size_t)NBH * QBLK * TILE_E;   // 16 MB each
    if (ws_size >= 2 * kv_elems * sizeof(unsigned short)) {
        unsigned short* Kw = (unsigned short*)d_ws;
        unsigned short* Vw = Kw + kv_elems;
        preconv_kernel<<<dim3(NBH * QBLK), dim3(256), 0, stream>>>(k, v, Kw, Vw);
        fattn_kernel<true><<<dim3(1024), dim3(128), 0, stream>>>(q, k, v, out, Kw, Vw);
    } else {
        fattn_kernel<false><<<dim3(1024), dim3(128), 0, stream>>>(q, k, v, out, nullptr, nullptr);
    }
}

// Round 5
// 251.736 us; speedup vs baseline: 1.5456x; 1.5456x over previous
//
#include <hip/hip_runtime.h>

// Causal flash attention, B=4 H=16 S=2048 D=64, fp32 in/out, bf16 MFMA.
// R5 = R4 structure (wave-per-64-row-strip, barrier-free, direct global->VGPR
// K/V frags from preconv'd fragment-linear images) with the spill fixed:
//  - S computed TRANSPOSED (mfma(Kfrag,Qfrag) -> S^T): C-layout rows = keys,
//    so P packs to b64 LDS writes in [qrow][key] layout; A-frag reads b128.
//  - score tile processed in two 32-key halves: sf = 32 VGPRs, af reuses its
//    slots => peak live ~220 VGPRs (R4: ~272 -> spilled 440MB to scratch).
//  - Q pre-scaled by 1/sqrt(D)*log2(e) at frag build (no per-score mul).
//  - XCD-affine mapping: bx&7 -> XCD, 8 heads/XCD => L2-resident K/V images.

#define S_LEN 2048
#define D_HEAD 64
#define NBH 64      // B*H
#define QBLK 32     // S / 64 (64-row strips)
#define TILE_E 4096 // 64x64 elements per tile image

typedef float f32x4 __attribute__((ext_vector_type(4)));
typedef short s16x8 __attribute__((ext_vector_type(8)));

#define SCLOG2E (0.125f * 1.44269504088896340736f)  // 1/sqrt(D) * log2(e)

__device__ __forceinline__ unsigned short f2bf(float x) {  // RNE
    union { float f; unsigned int u; } v; v.f = x;
    unsigned int u = v.u + 0x7FFFu + ((v.u >> 16) & 1u);
    return (unsigned short)(u >> 16);
}

// chunk-rotation swizzle for 64-wide bf16 rows (verified: 0 bank conflicts)
__device__ __forceinline__ int swz(int row, int col) {
    return row * 64 + ((((col >> 3) + row) & 7) << 3) + (col & 7);
}

// ---------- pre-pass: fp32 K,V -> bf16 FRAGMENT-LINEAR tile images ----------
// Image layout per 64x64 tile: idx = inst*512 + lane*8 + e, inst = kt2*4+nt.
// Kw: K[key=nt*16+(lane&15)][d=(4*kt2+(lane>>4))*8+e]
// Vw: V[key=(4*kt2+(lane>>4))*8+e][d=nt*16+(lane&15)]
__global__ __launch_bounds__(256)
void preconv_kernel(const float* __restrict__ K, const float* __restrict__ V,
                    unsigned short* __restrict__ Kw, unsigned short* __restrict__ Vw)
{
    __shared__ __align__(16) unsigned short kt[TILE_E];  // [key][d] swizzled
    __shared__ __align__(16) unsigned short vt[TILE_E];  // [d][key] swizzled
    const int bh = blockIdx.x & (NBH - 1);
    const int j  = blockIdx.x >> 6;
    const float* k = K + (size_t)bh * (S_LEN * D_HEAD) + (size_t)j * 64 * D_HEAD;
    const float* v = V + (size_t)bh * (S_LEN * D_HEAD) + (size_t)j * 64 * D_HEAD;
    const int t = threadIdx.x;

#pragma unroll
    for (int i = 0; i < 2; ++i) {   // K tile, row-major [key][d], swizzled
        int chunk = t + 256 * i;
        int row = chunk >> 3, c = chunk & 7;
        const float* p = k + (size_t)row * D_HEAD + c * 8;
        float4 x = *(const float4*)p;
        float4 y = *(const float4*)(p + 4);
        s16x8 f;
        f[0] = (short)f2bf(x.x); f[1] = (short)f2bf(x.y);
        f[2] = (short)f2bf(x.z); f[3] = (short)f2bf(x.w);
        f[4] = (short)f2bf(y.x); f[5] = (short)f2bf(y.y);
        f[6] = (short)f2bf(y.z); f[7] = (short)f2bf(y.w);
        *(s16x8*)&kt[swz(row, c * 8)] = f;
    }
    {   // V tile, transposed [d][key], swizzled
        int key = t & 63, cc = t >> 6;
#pragma unroll
        for (int ci = 0; ci < 2; ++ci) {
            int c = cc + ci * 4;
            const float* p = v + (size_t)key * D_HEAD + c * 8;
            float4 x = *(const float4*)p;
            float4 y = *(const float4*)(p + 4);
            float vals[8] = {x.x, x.y, x.z, x.w, y.x, y.y, y.z, y.w};
#pragma unroll
            for (int jj = 0; jj < 8; ++jj)
                vt[swz(c * 8 + jj, key)] = f2bf(vals[jj]);
        }
    }
    __syncthreads();
    const size_t tb = (size_t)(bh * QBLK + j) * TILE_E;
    const int w = t >> 6, lane = t & 63, col = lane & 15, quad = lane >> 4;
#pragma unroll
    for (int i = 0; i < 2; ++i) {
        int inst = w * 2 + i;
        int kt2 = inst >> 2, nt = inst & 3;
        s16x8 kf = *(const s16x8*)&kt[swz(nt * 16 + col, (4 * kt2 + quad) * 8)];
        s16x8 vf = *(const s16x8*)&vt[swz(nt * 16 + col, (4 * kt2 + quad) * 8)];
        *(s16x8*)&Kw[tb + inst * 512 + lane * 8] = kf;
        *(s16x8*)&Vw[tb + inst * 512 + lane * 8] = vf;
    }
}

// ---------------------------- main kernel -----------------------------------
template <bool PRE>
__global__ __launch_bounds__(128, 2)
void fattn_kernel(const float* __restrict__ Qg, const float* __restrict__ Kg,
                  const float* __restrict__ Vg, float* __restrict__ Og,
                  const unsigned short* __restrict__ Kw,
                  const unsigned short* __restrict__ Vw)
{
    __shared__ __align__(16) unsigned short ps[2][TILE_E];  // per-wave P [qrow][key]

    const int bx  = blockIdx.x;
    const int xcd = bx & 7;               // heuristic XCD partition (perf only)
    const int idx = bx >> 3;              // 0..127
    const int bh  = xcd * 8 + (idx & 7);  // 8 heads per XCD -> L2-resident images
    const int pr  = idx >> 3;             // 0..15 strip pair

    const int t    = threadIdx.x;
    const int w    = t >> 6;
    const int lane = t & 63;
    const int col  = lane & 15;
    const int quad = lane >> 4;
    const int qs   = w ? (15 - pr) : (16 + pr);   // equal block work (33 tiles)

    const size_t base = (size_t)bh * (S_LEN * D_HEAD);
    const float* q = Qg + base;
    const float* k = Kg + base;
    const float* v = Vg + base;
    float*       o = Og + base;

    // Q fragments (B-operand for S^T = K*Q^T), PRE-SCALED by 1/sqrt(D)*log2e
    s16x8 qa[4][2];
#pragma unroll
    for (int m = 0; m < 4; ++m) {
        const int qr = qs * 64 + m * 16 + col;
        const float* p0 = q + (size_t)qr * D_HEAD + quad * 8;
#pragma unroll
        for (int kt2 = 0; kt2 < 2; ++kt2) {
            const float* p = p0 + kt2 * 32;
            float4 x = *(const float4*)(p);
            float4 y = *(const float4*)(p + 4);
            s16x8 f;
            f[0] = (short)f2bf(x.x * SCLOG2E); f[1] = (short)f2bf(x.y * SCLOG2E);
            f[2] = (short)f2bf(x.z * SCLOG2E); f[3] = (short)f2bf(x.w * SCLOG2E);
            f[4] = (short)f2bf(y.x * SCLOG2E); f[5] = (short)f2bf(y.y * SCLOG2E);
            f[6] = (short)f2bf(y.z * SCLOG2E); f[7] = (short)f2bf(y.w * SCLOG2E);
            qa[m][kt2] = f;
        }
    }

    s16x8 ones;
#pragma unroll
    for (int i = 0; i < 8; ++i) ones[i] = (short)0x3F80;  // bf16 1.0

    f32x4 oacc[4][4], lf[4];
#pragma unroll
    for (int m = 0; m < 4; ++m) {
        lf[m] = (f32x4){0.f, 0.f, 0.f, 0.f};
#pragma unroll
        for (int nt = 0; nt < 4; ++nt) oacc[m][nt] = (f32x4){0.f, 0.f, 0.f, 0.f};
    }

    s16x8 kb2[2][4], vb[2][4];   // K: A-operand frags; V: B-operand frags

    auto loadK = [&](int jt) {
        if constexpr (PRE) {
            const unsigned short* tbp = Kw + (size_t)(bh * QBLK + jt) * TILE_E + lane * 8;
#pragma unroll
            for (int kt2 = 0; kt2 < 2; ++kt2)
#pragma unroll
                for (int nt = 0; nt < 4; ++nt)
                    kb2[kt2][nt] = *(const s16x8*)(tbp + (kt2 * 4 + nt) * 512);
        } else {
#pragma unroll
            for (int kt2 = 0; kt2 < 2; ++kt2)
#pragma unroll
                for (int nt = 0; nt < 4; ++nt) {
                    const float* p = k + (size_t)(jt * 64 + nt * 16 + col) * D_HEAD + (4 * kt2 + quad) * 8;
                    float4 x = *(const float4*)p;
                    float4 y = *(const float4*)(p + 4);
                    s16x8 f;
                    f[0] = (short)f2bf(x.x); f[1] = (short)f2bf(x.y);
                    f[2] = (short)f2bf(x.z); f[3] = (short)f2bf(x.w);
                    f[4] = (short)f2bf(y.x); f[5] = (short)f2bf(y.y);
                    f[6] = (short)f2bf(y.z); f[7] = (short)f2bf(y.w);
                    kb2[kt2][nt] = f;
                }
        }
    };
    auto loadV = [&](int jt) {
        if constexpr (PRE) {
            const unsigned short* tbp = Vw + (size_t)(bh * QBLK + jt) * TILE_E + lane * 8;
#pragma unroll
            for (int kt2 = 0; kt2 < 2; ++kt2)
#pragma unroll
                for (int nt = 0; nt < 4; ++nt)
                    vb[kt2][nt] = *(const s16x8*)(tbp + (kt2 * 4 + nt) * 512);
        } else {
#pragma unroll
            for (int kt2 = 0; kt2 < 2; ++kt2)
#pragma unroll
                for (int nt = 0; nt < 4; ++nt) {
                    s16x8 f;
#pragma unroll
                    for (int e = 0; e < 8; ++e)
                        f[e] = (short)f2bf(v[(size_t)(jt * 64 + (4 * kt2 + quad) * 8 + e) * D_HEAD + nt * 16 + col]);
                    vb[kt2][nt] = f;
                }
        }
    };

    loadK(0);
    loadV(0);

    for (int j = 0; j <= qs; ++j) {
        const bool diag = (j == qs);
        // ---- S^T = K Q^T in two 32-key halves; P packed to LDS [qrow][key]
#pragma unroll
        for (int h = 0; h < 2; ++h) {
            f32x4 sf[2][4];   // [i = key-subtile within half][mQ]
#pragma unroll
            for (int i = 0; i < 2; ++i)
#pragma unroll
                for (int m = 0; m < 4; ++m) sf[i][m] = (f32x4){0.f, 0.f, 0.f, 0.f};
#pragma unroll
            for (int kt2 = 0; kt2 < 2; ++kt2)
#pragma unroll
                for (int i = 0; i < 2; ++i)
#pragma unroll
                    for (int m = 0; m < 4; ++m)
                        sf[i][m] = __builtin_amdgcn_mfma_f32_16x16x32_bf16(
                            kb2[kt2][h * 2 + i], qa[m][kt2], sf[i][m], 0, 0, 0);

            // mask (diag only) + exp2 + pack pairs + b64 LDS write
#pragma unroll
            for (int i = 0; i < 2; ++i) {
                const int ntK = h * 2 + i;
#pragma unroll
                for (int m = 0; m < 4; ++m) {
                    if (diag) {
                        const int keyb = ntK * 16 + quad * 4;   // in-tile key of r=0
                        const int qrl  = m * 16 + col;          // in-tile q-row
#pragma unroll
                        for (int r = 0; r < 4; ++r)
                            if (keyb + r > qrl) sf[i][m][r] = -__builtin_inff();
                    }
                    unsigned p0 = __float_as_uint(exp2f(sf[i][m][0])) + 0x8000u;
                    unsigned p1 = __float_as_uint(exp2f(sf[i][m][1])) + 0x8000u;
                    unsigned p2 = __float_as_uint(exp2f(sf[i][m][2])) + 0x8000u;
                    unsigned p3 = __float_as_uint(exp2f(sf[i][m][3])) + 0x8000u;
                    uint2 pk;
                    pk.x = __builtin_amdgcn_perm(p1, p0, 0x07060302);
                    pk.y = __builtin_amdgcn_perm(p3, p2, 0x07060302);
                    *(uint2*)&ps[w][swz(m * 16 + col, ntK * 16 + quad * 4)] = pk;
                }
            }
        }

        // ---- prefetch K for next tile (kb2 now dead)
        const int jn = (j < qs) ? (j + 1) : qs;
        loadK(jn);

        // ---- P A-frags (in-wave LDS ordering; no barrier)
        s16x8 af[4][2];
#pragma unroll
        for (int m = 0; m < 4; ++m)
#pragma unroll
            for (int kt2 = 0; kt2 < 2; ++kt2)
                af[m][kt2] = *(const s16x8*)&ps[w][swz(m * 16 + col, (4 * kt2 + quad) * 8)];

        // ---- l += P*ones ; O += P V
#pragma unroll
        for (int m = 0; m < 4; ++m)
#pragma unroll
            for (int kt2 = 0; kt2 < 2; ++kt2)
                lf[m] = __builtin_amdgcn_mfma_f32_16x16x32_bf16(af[m][kt2], ones, lf[m], 0, 0, 0);
#pragma unroll
        for (int kt2 = 0; kt2 < 2; ++kt2)
#pragma unroll
            for (int nt = 0; nt < 4; ++nt)
#pragma unroll
                for (int m = 0; m < 4; ++m)
                    oacc[m][nt] = __builtin_amdgcn_mfma_f32_16x16x32_bf16(af[m][kt2], vb[kt2][nt], oacc[m][nt], 0, 0, 0);

        // ---- prefetch V for next tile (vb now dead)
        loadV(jn);
    }

    // ---- epilogue (C-layout: row = quad*4+r, col = lane&15)
#pragma unroll
    for (int m = 0; m < 4; ++m)
#pragma unroll
        for (int r = 0; r < 4; ++r) {
            float inv = 1.f / lf[m][r];
            int row = qs * 64 + m * 16 + quad * 4 + r;
            float* po = o + (size_t)row * D_HEAD;
#pragma unroll
            for (int nt = 0; nt < 4; ++nt) po[nt * 16 + col] = oacc[m][nt][r] * inv;
        }
}

extern "C" void kernel_launch(void* const* d_in, const int* in_sizes, int n_in,
                              void* d_out, int out_size, void* d_ws, size_t ws_size,
                              hipStream_t stream) {
    const float* q = (const float*)d_in[0];
    const float* k = (const float*)d_in[1];
    const float* v = (const float*)d_in[2];
    float* out = (float*)d_out;

    const size_t kv_elems = (size_t)NBH * QBLK * TILE_E;   // 16 MB each
    if (ws_size >= 2 * kv_elems * sizeof(unsigned short)) {
        unsigned short* Kw = (unsigned short*)d_ws;
        unsigned short* Vw = Kw + kv_elems;
        preconv_kernel<<<dim3(NBH * QBLK), dim3(256), 0, stream>>>(k, v, Kw, Vw);
        fattn_kernel<true><<<dim3(1024), dim3(128), 0, stream>>>(q, k, v, out, Kw, Vw);
    } else {
        fattn_kernel<false><<<dim3(1024), dim3(128), 0, stream>>>(q, k, v, out, nullptr, nullptr);
    }
}